// Round 3
// baseline (2272.775 us; speedup 1.0000x reference)
//
#include <hip/hip_runtime.h>
#include <stdint.h>

#define N 2048
#define BATCH 8
#define NROWS (BATCH * N)   // 16384
#define CAPN 256            // shortlist capacity per row
#define KPL 4               // key slots per lane (CAPN/64)
#define RCH 4               // rows per chunk
#define CHUNKS (N / RCH)    // 512 (even)

typedef unsigned long long u64;
typedef unsigned u32;

#define DEADK 0xFFFFFFFFFFFFFFFFull

// ---------------- DPP reductions ------------------------------------------
// row_shr 1,2,4,8 then row_bcast15, row_bcast31: min lands in lane 63.
// bound_ctrl=false + old=x keeps own value on invalid lanes (identity for min).
__device__ __forceinline__ unsigned wave_umin_bcast(unsigned x) {
#define DPP_MIN(ctrl)                                                          \
  {                                                                            \
    unsigned t = (unsigned)__builtin_amdgcn_update_dpp((int)x, (int)x, ctrl,   \
                                                       0xf, 0xf, false);       \
    x = t < x ? t : x;                                                         \
  }
  DPP_MIN(0x111) DPP_MIN(0x112) DPP_MIN(0x114) DPP_MIN(0x118)
  DPP_MIN(0x142) DPP_MIN(0x143)
#undef DPP_MIN
  return (unsigned)__builtin_amdgcn_readlane((int)x, 63);
}

__device__ __forceinline__ unsigned wave_umax_bcast(unsigned x) {
#define DPP_MAX(ctrl)                                                          \
  {                                                                            \
    unsigned t = (unsigned)__builtin_amdgcn_update_dpp((int)x, (int)x, ctrl,   \
                                                       0xf, 0xf, false);       \
    x = t > x ? t : x;                                                         \
  }
  DPP_MAX(0x111) DPP_MAX(0x112) DPP_MAX(0x114) DPP_MAX(0x118)
  DPP_MAX(0x142) DPP_MAX(0x143)
#undef DPP_MAX
  return (unsigned)__builtin_amdgcn_readlane((int)x, 63);
}

#define DPP64_MIN(x, ctrl)                                                     \
  {                                                                            \
    u32 lo_ = (u32)(x), hi_ = (u32)((x) >> 32);                                \
    u32 tlo_ = (u32)__builtin_amdgcn_update_dpp((int)lo_, (int)lo_, (ctrl),    \
                                                0xf, 0xf, false);              \
    u32 thi_ = (u32)__builtin_amdgcn_update_dpp((int)hi_, (int)hi_, (ctrl),    \
                                                0xf, 0xf, false);              \
    u64 t_ = ((u64)thi_ << 32) | tlo_;                                         \
    x = t_ < x ? t_ : x;                                                       \
  }

__device__ __forceinline__ u64 wave_min64_l63(u64 x) {
  DPP64_MIN(x, 0x111) DPP64_MIN(x, 0x112) DPP64_MIN(x, 0x114)
  DPP64_MIN(x, 0x118) DPP64_MIN(x, 0x142) DPP64_MIN(x, 0x143)
  return x;
}

// Exact-order distance: ((dx*dx + dy*dy) + dz*dz), no FMA contraction, sqrtf.
#define DIST(qx, qy, qz, TX, TY, TZ, j, dout)                                  \
  do {                                                                         \
    _Pragma("clang fp contract(off)")                                          \
    float dx_ = (qx) - (TX)[j];                                                \
    float dy_ = (qy) - (TY)[j];                                                \
    float dz_ = (qz) - (TZ)[j];                                                \
    float s_ = dx_ * dx_ + dy_ * dy_ + dz_ * dz_;                              \
    dout = sqrtf(s_);                                                          \
  } while (0)

// ---------------- Phase 1: parallel shortlist precompute (unchanged) ------
// One wave per row. tau = wave-max over lane-pair minima guarantees >= 32
// entries <= tau; {d <= tau} is prefix-closed under the (d,j) order.
__global__ __launch_bounds__(256, 1)
void emd_shortlist_kernel(const float* __restrict__ pred,
                          const float* __restrict__ target,
                          u64* __restrict__ keys,
                          u32* __restrict__ cnts) {
    __shared__ float tx[N], ty[N], tz[N];
    const int b  = blockIdx.x >> 9;          // 512 blocks per batch
    const int r0 = (blockIdx.x & 511) << 2;  // 4 rows per block
    const float* tb = target + (size_t)b * N * 3;

    for (int idx = threadIdx.x; idx < 3 * N; idx += 256) {
        float v = tb[idx];
        int n = idx / 3, c = idx - 3 * n;
        if (c == 0) tx[n] = v; else if (c == 1) ty[n] = v; else tz[n] = v;
    }
    __syncthreads();

    const int wid = threadIdx.x >> 6, lane = threadIdx.x & 63;
    const int i = r0 + wid;
    const size_t row = (size_t)b * N + i;
    const float* pb = pred + row * 3;
    const float qx = pb[0], qy = pb[1], qz = pb[2];

    float d[32];
    float m = 3.4e38f;
    #pragma unroll
    for (int c = 0; c < 32; ++c) {
        const int j = (c << 6) + lane;
        float dd;
        DIST(qx, qy, qz, tx, ty, tz, j, dd);
        d[c] = dd;
        m = fminf(m, dd);
    }

    // pair minima via quad_perm xor1, then tau = wave max
    unsigned mb = __float_as_uint(m);
    {
        unsigned t = (unsigned)__builtin_amdgcn_update_dpp((int)mb, (int)mb,
                                                           0x0B1, 0xf, 0xf, false);
        mb = t < mb ? t : mb;
    }
    const unsigned tau = wave_umax_bcast(mb);
    const float tauf = __uint_as_float(tau);

    u64* krow = keys + row * (size_t)CAPN;
    unsigned base = 0;
    #pragma unroll
    for (int c = 0; c < 32; ++c) {
        const bool p = d[c] <= tauf;
        const u64 bm = __ballot(p);
        if (p) {
            unsigned off = base + (unsigned)__popcll(bm & ((1ull << lane) - 1ull));
            if (off < (unsigned)CAPN)
                krow[off] = ((u64)__float_as_uint(d[c]) << 32) |
                            (unsigned)((c << 6) + lane);
        }
        base += (unsigned)__popcll(bm);
    }
    if (lane == 0) cnts[row] = base;   // may exceed CAPN -> row full-scans
}

// ---------------- exact full-scan fallback (rare; used[] is complete) -----
__device__ __noinline__ u64 full_scan_row(
    int lane, float qx, float qy, float qz,
    const float* tx, const float* ty, const float* tz,
    const unsigned char* used) {
  u32 dl = 0xFFFFFFFFu, jl = 0u;
  #pragma unroll 8
  for (int c = 0; c < 32; ++c) {
    const int j = (c << 6) + lane;
    if (!used[j]) {
      float dd;
      DIST(qx, qy, qz, tx, ty, tz, j, dd);
      const u32 db = __float_as_uint(dd);
      if (db < dl) { dl = db; jl = (u32)j; }
    }
  }
  const u32 dmin = wave_umin_bcast(dl);
  const u32 jc = (dl == dmin) ? jl : 0xFFFFFFFFu;
  const u32 jmin = wave_umin_bcast(jc);
  return ((u64)dmin << 32) | jmin;
}

// ---------------- Phase 2: greedy with register keys + lazy ring ----------
__global__ __launch_bounds__(64, 1)
void emd_greedy_ring_kernel(const float* __restrict__ pred,
                            const float* __restrict__ target,
                            const u64* __restrict__ keys,
                            const u32* __restrict__ cnts,
                            float* __restrict__ batch_emd) {
    __shared__ float tx[N], ty[N], tz[N];
    __shared__ float qxs[N], qys[N], qzs[N];
    __shared__ unsigned char used[N];

    const int lane = threadIdx.x;
    const int b = blockIdx.x;
    const float* pb = pred + (size_t)b * N * 3;
    const float* tb = target + (size_t)b * N * 3;

    for (int idx = lane; idx < 3 * N; idx += 64) {
        float vp = pb[idx], vt = tb[idx];
        int n = idx / 3, c = idx - 3 * n;
        if (c == 0)      { qxs[n] = vp; tx[n] = vt; }
        else if (c == 1) { qys[n] = vp; ty[n] = vt; }
        else             { qzs[n] = vp; tz[n] = vt; }
    }
    for (int j = lane; j < N; j += 64) used[j] = 0;
    // single wave: LDS is program-ordered, no barrier needed

    const size_t rowbase = (size_t)b * N;
    double sum = 0.0;

    u64 Ga[RCH][KPL], Gb[RCH][KPL];   // raw loaded keys
    u64 Pa[RCH][KPL], Pb[RCH][KPL];   // alive keys (DEADK = dead)
    u32 Ca[RCH], Cb[RCH];
    u32 rg[8];
    #pragma unroll
    for (int t = 0; t < 8; ++t) rg[t] = 0xFFFFFFFFu;

    auto LOADG = [&](u64 (&G)[RCH][KPL], u32 (&C)[RCH], int ch) {
        #pragma unroll
        for (int r = 0; r < RCH; ++r) {
            const size_t row = rowbase + (size_t)ch * RCH + r;
            const u64* kp = keys + row * (size_t)CAPN;
            #pragma unroll
            for (int k = 0; k < KPL; ++k) G[r][k] = kp[lane + (k << 6)];
            C[r] = cnts[row];
        }
    };

    auto INITP = [&](u64 (&P)[RCH][KPL], u64 (&G)[RCH][KPL], u32 (&C)[RCH]) {
        #pragma unroll
        for (int r = 0; r < RCH; ++r) {
            const bool ovf = C[r] > (u32)CAPN;
            #pragma unroll
            for (int k = 0; k < KPL; ++k) {
                const u32 e = (u32)lane + (u32)(k << 6);
                const u64 key = G[r][k];
                const u32 j = (u32)key & (N - 1);
                const bool dead = ovf || (e >= C[r]) || (used[j] != 0);
                P[r][k] = dead ? DEADK : key;
            }
        }
    };

    auto PROCESS = [&](u64 (&P)[RCH][KPL], int ch) {
        #pragma unroll
        for (int r = 0; r < RCH; ++r) {
            const int i = ch * RCH + r;
            u64 m01 = P[r][0] < P[r][1] ? P[r][0] : P[r][1];
            u64 m23 = P[r][2] < P[r][3] ? P[r][2] : P[r][3];
            u64 m = m01 < m23 ? m01 : m23;
            u64 wm = wave_min64_l63(m);
            u32 dw = (u32)__builtin_amdgcn_readlane((int)(u32)(wm >> 32), 63);
            u32 jw = (u32)__builtin_amdgcn_readlane((int)(u32)wm, 63);

            for (;;) {
                if (dw == 0xFFFFFFFFu) {   // exhausted or overflow row
                    u64 fs = full_scan_row(lane, qxs[i], qys[i], qzs[i],
                                           tx, ty, tz, used);
                    dw = (u32)(fs >> 32);
                    jw = (u32)fs;
                    break;                  // used[] complete -> result final
                }
                bool hit = false;
                #pragma unroll
                for (int t = 0; t < 8; ++t) hit |= (jw == rg[t]);
                if (!hit) break;
                // stale winner: kill it in this row's slots, recompute
                #pragma unroll
                for (int k = 0; k < KPL; ++k)
                    if ((u32)P[r][k] == jw) P[r][k] = DEADK;
                m01 = P[r][0] < P[r][1] ? P[r][0] : P[r][1];
                m23 = P[r][2] < P[r][3] ? P[r][2] : P[r][3];
                m = m01 < m23 ? m01 : m23;
                wm = wave_min64_l63(m);
                dw = (u32)__builtin_amdgcn_readlane((int)(u32)(wm >> 32), 63);
                jw = (u32)__builtin_amdgcn_readlane((int)(u32)wm, 63);
            }

            // commit: ring push, sum, mark used
            #pragma unroll
            for (int t = 7; t > 0; --t) rg[t] = rg[t - 1];
            rg[0] = jw;
            sum += (double)__uint_as_float(dw);
            if (lane == 0) used[jw] = 1;
        }
    };

    // prologue: fill pipeline
    LOADG(Ga, Ca, 0);
    INITP(Pa, Ga, Ca);         // chunk 0 (one-time vmcnt stall)
    LOADG(Gb, Cb, 1);

    for (int c = 0; c < CHUNKS; c += 2) {
        if (c + 2 < CHUNKS) LOADG(Ga, Ca, c + 2);
        INITP(Pb, Gb, Cb);                       // chunk c+1 (Gb landed)
        PROCESS(Pa, c);
        if (c + 3 < CHUNKS) LOADG(Gb, Cb, c + 3);
        if (c + 2 < CHUNKS) INITP(Pa, Ga, Ca);   // chunk c+2
        PROCESS(Pb, c + 1);
    }

    if (lane == 0) batch_emd[b] = (float)(sum / N);
}

// ---------------- Fallback: full-scan-only greedy (tiny ws) ---------------
__global__ __launch_bounds__(64, 1)
void emd_greedy_full_kernel(const float* __restrict__ pred,
                            const float* __restrict__ target,
                            float* __restrict__ batch_emd) {
    __shared__ float tx[N], ty[N], tz[N];
    __shared__ float qxs[N], qys[N], qzs[N];
    __shared__ unsigned char used[N];

    const int lane = threadIdx.x;
    const int b = blockIdx.x;
    const float* pb = pred + (size_t)b * N * 3;
    const float* tb = target + (size_t)b * N * 3;

    for (int idx = lane; idx < 3 * N; idx += 64) {
        float vp = pb[idx], vt = tb[idx];
        int n = idx / 3, c = idx - 3 * n;
        if (c == 0)      { qxs[n] = vp; tx[n] = vt; }
        else if (c == 1) { qys[n] = vp; ty[n] = vt; }
        else             { qzs[n] = vp; tz[n] = vt; }
    }
    for (int j = lane; j < N; j += 64) used[j] = 0;

    double sum = 0.0;
    for (int i = 0; i < N; ++i) {
        u64 fs = full_scan_row(lane, qxs[i], qys[i], qzs[i], tx, ty, tz, used);
        sum += (double)__uint_as_float((u32)(fs >> 32));
        if (lane == 0) used[(u32)fs] = 1;
    }
    if (lane == 0) batch_emd[b] = (float)(sum / N);
}

__global__ void emd_mean_kernel(const float* __restrict__ batch_emd,
                                float* __restrict__ out) {
    double s = 0.0;
    for (int b = 0; b < BATCH; ++b) s += (double)batch_emd[b];
    out[0] = (float)(s / BATCH);
}

extern "C" void kernel_launch(void* const* d_in, const int* in_sizes, int n_in,
                              void* d_out, int out_size, void* d_ws, size_t ws_size,
                              hipStream_t stream) {
    const float* pred   = (const float*)d_in[0];
    const float* target = (const float*)d_in[1];
    float* out = (float*)d_out;
    char* wsb = (char*)d_ws;

    const size_t keysz = (size_t)NROWS * CAPN * 8;   // 33.6 MB
    const size_t cntsz = (size_t)NROWS * 4;

    if (ws_size >= keysz + cntsz + 32) {
        u64* keys = (u64*)wsb;
        u32* cnts = (u32*)(wsb + keysz);
        float* emd = (float*)(wsb + keysz + cntsz);
        emd_shortlist_kernel<<<NROWS / 4, 256, 0, stream>>>(pred, target, keys, cnts);
        emd_greedy_ring_kernel<<<BATCH, 64, 0, stream>>>(pred, target, keys, cnts, emd);
        emd_mean_kernel<<<1, 1, 0, stream>>>(emd, out);
    } else {
        float* emd = (float*)wsb;
        emd_greedy_full_kernel<<<BATCH, 64, 0, stream>>>(pred, target, emd);
        emd_mean_kernel<<<1, 1, 0, stream>>>(emd, out);
    }
}

// Round 4
// 1202.848 us; speedup vs baseline: 1.8895x; 1.8895x over previous
//
#include <hip/hip_runtime.h>
#include <stdint.h>

#define N 2048
#define BATCH 8
#define NROWS (BATCH * N)   // 16384
#define CAPN 256            // shortlist capacity per row
#define DEPTH 8             // phase-2 pipeline depth (rows in flight)

typedef unsigned long long u64;
typedef unsigned u32;

#define DEADK 0xFFFFFFFFFFFFFFFFull

// ---------------- DPP wave64 reductions -----------------------------------
__device__ __forceinline__ unsigned wave_umin_bcast(unsigned x) {
#define DPP_MIN(ctrl)                                                          \
  {                                                                            \
    unsigned t = (unsigned)__builtin_amdgcn_update_dpp((int)x, (int)x, ctrl,   \
                                                       0xf, 0xf, false);       \
    x = t < x ? t : x;                                                         \
  }
  DPP_MIN(0x111) DPP_MIN(0x112) DPP_MIN(0x114) DPP_MIN(0x118)
  DPP_MIN(0x142) DPP_MIN(0x143)
#undef DPP_MIN
  return (unsigned)__builtin_amdgcn_readlane((int)x, 63);
}

__device__ __forceinline__ unsigned wave_umax_bcast(unsigned x) {
#define DPP_MAX(ctrl)                                                          \
  {                                                                            \
    unsigned t = (unsigned)__builtin_amdgcn_update_dpp((int)x, (int)x, ctrl,   \
                                                       0xf, 0xf, false);       \
    x = t > x ? t : x;                                                         \
  }
  DPP_MAX(0x111) DPP_MAX(0x112) DPP_MAX(0x114) DPP_MAX(0x118)
  DPP_MAX(0x142) DPP_MAX(0x143)
#undef DPP_MAX
  return (unsigned)__builtin_amdgcn_readlane((int)x, 63);
}

#define DPP64_MIN(x, ctrl)                                                     \
  {                                                                            \
    u32 lo_ = (u32)(x), hi_ = (u32)((x) >> 32);                                \
    u32 tlo_ = (u32)__builtin_amdgcn_update_dpp((int)lo_, (int)lo_, (ctrl),    \
                                                0xf, 0xf, false);              \
    u32 thi_ = (u32)__builtin_amdgcn_update_dpp((int)hi_, (int)hi_, (ctrl),    \
                                                0xf, 0xf, false);              \
    u64 t_ = ((u64)thi_ << 32) | tlo_;                                         \
    x = t_ < x ? t_ : x;                                                       \
  }

__device__ __forceinline__ u64 wave_min64_l63(u64 x) {
  DPP64_MIN(x, 0x111) DPP64_MIN(x, 0x112) DPP64_MIN(x, 0x114)
  DPP64_MIN(x, 0x118) DPP64_MIN(x, 0x142) DPP64_MIN(x, 0x143)
  return x;
}

// Exact-order distance: ((dx*dx + dy*dy) + dz*dz), no FMA contraction, sqrtf.
#define DIST(qx, qy, qz, TX, TY, TZ, j, dout)                                  \
  do {                                                                         \
    _Pragma("clang fp contract(off)")                                          \
    float dx_ = (qx) - (TX)[j];                                                \
    float dy_ = (qy) - (TY)[j];                                                \
    float dz_ = (qz) - (TZ)[j];                                                \
    float s_ = dx_ * dx_ + dy_ * dy_ + dz_ * dz_;                              \
    dout = sqrtf(s_);                                                          \
  } while (0)

// ---------------- Phase 1a: tau-shortlist (proven in R2) -------------------
// Shortlist = COMPLETE set {key : d <= tau}, prefix-closed under (d,j) order.
__global__ __launch_bounds__(256, 1)
void emd_shortlist_kernel(const float* __restrict__ pred,
                          const float* __restrict__ target,
                          u64* __restrict__ keys,
                          u32* __restrict__ cnts) {
    __shared__ float tx[N], ty[N], tz[N];
    const int b  = blockIdx.x >> 9;
    const int r0 = (blockIdx.x & 511) << 2;
    const float* tb = target + (size_t)b * N * 3;

    for (int idx = threadIdx.x; idx < 3 * N; idx += 256) {
        float v = tb[idx];
        int n = idx / 3, c = idx - 3 * n;
        if (c == 0) tx[n] = v; else if (c == 1) ty[n] = v; else tz[n] = v;
    }
    __syncthreads();

    const int wid = threadIdx.x >> 6, lane = threadIdx.x & 63;
    const int i = r0 + wid;
    const size_t row = (size_t)b * N + i;
    const float* pb = pred + row * 3;
    const float qx = pb[0], qy = pb[1], qz = pb[2];

    float d[32];
    float m = 3.4e38f;
    #pragma unroll
    for (int c = 0; c < 32; ++c) {
        const int j = (c << 6) + lane;
        float dd;
        DIST(qx, qy, qz, tx, ty, tz, j, dd);
        d[c] = dd;
        m = fminf(m, dd);
    }

    unsigned mb = __float_as_uint(m);
    {   // pair-min (xor1 quad_perm): tau = max of 32 min-of-64 -> E[cnt]~130
        unsigned t = (unsigned)__builtin_amdgcn_update_dpp((int)mb, (int)mb,
                                                           0x0B1, 0xf, 0xf, false);
        mb = t < mb ? t : mb;
    }
    const unsigned tau = wave_umax_bcast(mb);
    const float tauf = __uint_as_float(tau);

    u64* krow = keys + row * (size_t)CAPN;
    unsigned base = 0;
    #pragma unroll
    for (int c = 0; c < 32; ++c) {
        const bool p = d[c] <= tauf;
        const u64 bm = __ballot(p);
        if (p) {
            unsigned off = base + (unsigned)__popcll(bm & ((1ull << lane) - 1ull));
            if (off < (unsigned)CAPN)
                krow[off] = ((u64)__float_as_uint(d[c]) << 32) |
                            (unsigned)((c << 6) + lane);
        }
        base += (unsigned)__popcll(bm);
    }
    if (lane == 0) cnts[row] = base;
}

// ---------------- Phase 1b: in-place sorted top-64 extraction --------------
// One wave per row. Loads the full shortlist into regs (4 slots/lane = CAPN),
// then 64x (wave u64-min + pop). Lane `it` captures extraction `it`; final
// store: keys[row][lane] = lane-th smallest key (or DEADK). Exact: prefix of
// the prefix-closed tau-set = true global top-min(cnt,64). cnt>CAPN -> all
// DEADK (phase 2 full-scans those rows).
#define CSWAP(a, b)                                                            \
  { u64 mn_ = (a) < (b) ? (a) : (b); u64 mx_ = (a) < (b) ? (b) : (a);          \
    (a) = mn_; (b) = mx_; }

__global__ __launch_bounds__(256, 1)
void emd_sort64_kernel(u64* __restrict__ keys, const u32* __restrict__ cnts) {
    const int wid = threadIdx.x >> 6, lane = threadIdx.x & 63;
    const size_t row = (size_t)blockIdx.x * 4 + wid;
    u64* krow = keys + row * (size_t)CAPN;

    const u32 cnt = cnts[row];
    const u32 lim = (cnt > (u32)CAPN) ? 0u : cnt;   // overflow -> no candidates

    u64 k0 = ((u32)lane       < lim) ? krow[lane      ] : DEADK;
    u64 k1 = ((u32)lane + 64  < lim) ? krow[lane + 64 ] : DEADK;
    u64 k2 = ((u32)lane + 128 < lim) ? krow[lane + 128] : DEADK;
    u64 k3 = ((u32)lane + 192 < lim) ? krow[lane + 192] : DEADK;

    // sort4 ascending (network)
    CSWAP(k0, k1) CSWAP(k2, k3) CSWAP(k0, k2) CSWAP(k1, k3) CSWAP(k1, k2)

    u64 mykey = DEADK;
    for (int it = 0; it < 64; ++it) {
        u64 wm = wave_min64_l63(k0);
        u32 wlo = (u32)__builtin_amdgcn_readlane((int)(u32)wm, 63);
        u32 whi = (u32)__builtin_amdgcn_readlane((int)(u32)(wm >> 32), 63);
        if (whi == 0xFFFFFFFFu) break;            // all exhausted (cnt < 64)
        const u64 wkey = ((u64)whi << 32) | wlo;
        mykey = (lane == it) ? wkey : mykey;      // capture in lane `it`
        const bool eq = (k0 == wkey);             // unique (distinct j)
        k0 = eq ? k1 : k0; k1 = eq ? k2 : k1; k2 = eq ? k3 : k2;
        k3 = eq ? DEADK : k3;
    }
    krow[lane] = mykey;   // in-place: all reads consumed above
}

// ---------------- Phase 2: ballot-greedy, one wave per batch ---------------
__global__ __launch_bounds__(64, 1)
void emd_greedy_ballot_kernel(const float* __restrict__ pred,
                              const float* __restrict__ target,
                              const u64* __restrict__ keys,
                              float* __restrict__ batch_emd) {
    __shared__ float tx[N], ty[N], tz[N];
    __shared__ float qxs[N], qys[N], qzs[N];
    __shared__ u32 maskLDS[64];                  // 2048-bit consumed bitmask

    const int lane = threadIdx.x;
    const int b = blockIdx.x;
    const float* pb = pred + (size_t)b * N * 3;
    const float* tb = target + (size_t)b * N * 3;

    for (int idx = lane; idx < 3 * N; idx += 64) {
        float vp = pb[idx], vt = tb[idx];
        int n = idx / 3, c = idx - 3 * n;
        if (c == 0)      { qxs[n] = vp; tx[n] = vt; }
        else if (c == 1) { qys[n] = vp; ty[n] = vt; }
        else             { qzs[n] = vp; tz[n] = vt; }
    }
    maskLDS[lane] = 0;
    u32 mw = 0;                                  // lane l mirrors word l
    // single wave: LDS is program-ordered; no barriers needed

    const u64* kb = keys + (size_t)b * N * (size_t)CAPN;

    // ring of last-4 winners (uniform)
    u32 w0 = ~0u, w1 = ~0u, w2 = ~0u, w3 = ~0u;

    // pipeline: slot s holds candidates of one row; static indexing only
    u32 jn[DEPTH], dn[DEPTH], wrd[DEPTH];
    #pragma unroll
    for (int s = 0; s < DEPTH; ++s) {
        const u64 kk = kb[(size_t)s * CAPN + lane];
        jn[s] = (u32)kk; dn[s] = (u32)(kk >> 32); wrd[s] = 0;
    }

    double sum = 0.0;

    #pragma unroll 1
    for (int i0 = 0; i0 < N; i0 += DEPTH) {
        #pragma unroll
        for (int s = 0; s < DEPTH; ++s) {
            const int i = i0 + s;
            // ---- selection (branch-free hot path) ----
            const u32 jv = jn[s], dv = dn[s];
            const bool alive = (((wrd[s] >> (jv & 31)) & 1u) == 0u) &
                               (dv != 0xFFFFFFFFu) &
                               (jv != w0) & (jv != w1) & (jv != w2) & (jv != w3);
            const u64 bal = __ballot(alive);
            u32 dw, jw;
            if (bal) {                            // uniform branch, ~always
                const int L = __ffsll((long long)bal) - 1;
                dw = (u32)__builtin_amdgcn_readlane((int)dv, L);
                jw = (u32)__builtin_amdgcn_readlane((int)jv, L);
            } else {
                // exact full scan via bitmask (rare: ~60/batch)
                u32 dl = 0xFFFFFFFFu, jl = 0;
                const float qx = qxs[i], qy = qys[i], qz = qzs[i];
                #pragma unroll 1
                for (int c = 0; c < 32; ++c) {
                    const int j = (c << 6) + lane;
                    const u32 w = maskLDS[j >> 5];
                    float dd;
                    DIST(qx, qy, qz, tx, ty, tz, j, dd);
                    const u32 db = __float_as_uint(dd);
                    if ((((w >> (j & 31)) & 1u) == 0u) && db < dl) {
                        dl = db; jl = (u32)j;
                    }
                }
                const u32 dmin = wave_umin_bcast(dl);
                const u32 jc = (dl == dmin) ? jl : 0xFFFFFFFFu;
                const u32 jmin = wave_umin_bcast(jc);
                dw = dmin; jw = jmin;
            }
            // ---- commit ----
            sum += (double)__uint_as_float(dw);
            w3 = w2; w2 = w1; w1 = w0; w0 = jw;
            const u32 widx = jw >> 5, wbit = 1u << (jw & 31);
            if (lane == (int)widx) { mw |= wbit; maskLDS[lane] = mw; }
            // ---- deferred mask-word read for row i+2 (slot (s+2)&7) ----
            {
                constexpr int u = 0;  // placeholder to keep scope tidy
            }
            wrd[(s + 2) & (DEPTH - 1)] =
                maskLDS[(jn[(s + 2) & (DEPTH - 1)] >> 5) & 63];
            // ---- insert row i+DEPTH into slot s ----
            {
                int r2 = i + DEPTH; if (r2 > N - 1) r2 = N - 1;  // tail clamp
                const u64 kk = kb[(size_t)r2 * CAPN + lane];
                jn[s] = (u32)kk; dn[s] = (u32)(kk >> 32);
            }
        }
    }

    if (lane == 0) batch_emd[b] = (float)(sum / N);
}

// ---------------- exact full-scan helper (tiny-ws fallback kernel) --------
__device__ __forceinline__ u64 full_scan_row(
    int lane, float qx, float qy, float qz,
    const float* tx, const float* ty, const float* tz,
    const unsigned char* used) {
  u32 dl = 0xFFFFFFFFu, jl = 0u;
  #pragma unroll 8
  for (int c = 0; c < 32; ++c) {
    const int j = (c << 6) + lane;
    if (!used[j]) {
      float dd;
      DIST(qx, qy, qz, tx, ty, tz, j, dd);
      const u32 db = __float_as_uint(dd);
      if (db < dl) { dl = db; jl = (u32)j; }
    }
  }
  const u32 dmin = wave_umin_bcast(dl);
  const u32 jc = (dl == dmin) ? jl : 0xFFFFFFFFu;
  const u32 jmin = wave_umin_bcast(jc);
  return ((u64)dmin << 32) | jmin;
}

__global__ __launch_bounds__(64, 1)
void emd_greedy_full_kernel(const float* __restrict__ pred,
                            const float* __restrict__ target,
                            float* __restrict__ batch_emd) {
    __shared__ float tx[N], ty[N], tz[N];
    __shared__ float qxs[N], qys[N], qzs[N];
    __shared__ unsigned char used[N];

    const int lane = threadIdx.x;
    const int b = blockIdx.x;
    const float* pb = pred + (size_t)b * N * 3;
    const float* tb = target + (size_t)b * N * 3;

    for (int idx = lane; idx < 3 * N; idx += 64) {
        float vp = pb[idx], vt = tb[idx];
        int n = idx / 3, c = idx - 3 * n;
        if (c == 0)      { qxs[n] = vp; tx[n] = vt; }
        else if (c == 1) { qys[n] = vp; ty[n] = vt; }
        else             { qzs[n] = vp; tz[n] = vt; }
    }
    for (int j = lane; j < N; j += 64) used[j] = 0;

    double sum = 0.0;
    for (int i = 0; i < N; ++i) {
        u64 fs = full_scan_row(lane, qxs[i], qys[i], qzs[i], tx, ty, tz, used);
        sum += (double)__uint_as_float((u32)(fs >> 32));
        if (lane == 0) used[(u32)fs] = 1;
    }
    if (lane == 0) batch_emd[b] = (float)(sum / N);
}

__global__ void emd_mean_kernel(const float* __restrict__ batch_emd,
                                float* __restrict__ out) {
    double s = 0.0;
    for (int b = 0; b < BATCH; ++b) s += (double)batch_emd[b];
    out[0] = (float)(s / BATCH);
}

extern "C" void kernel_launch(void* const* d_in, const int* in_sizes, int n_in,
                              void* d_out, int out_size, void* d_ws, size_t ws_size,
                              hipStream_t stream) {
    const float* pred   = (const float*)d_in[0];
    const float* target = (const float*)d_in[1];
    float* out = (float*)d_out;
    char* wsb = (char*)d_ws;

    const size_t keysz = (size_t)NROWS * CAPN * 8;   // 33.6 MB
    const size_t cntsz = (size_t)NROWS * 4;

    if (ws_size >= keysz + cntsz + 32) {
        u64* keys = (u64*)wsb;
        u32* cnts = (u32*)(wsb + keysz);
        float* emd = (float*)(wsb + keysz + cntsz);
        emd_shortlist_kernel<<<NROWS / 4, 256, 0, stream>>>(pred, target, keys, cnts);
        emd_sort64_kernel<<<NROWS / 4, 256, 0, stream>>>(keys, cnts);
        emd_greedy_ballot_kernel<<<BATCH, 64, 0, stream>>>(pred, target, keys, emd);
        emd_mean_kernel<<<1, 1, 0, stream>>>(emd, out);
    } else {
        float* emd = (float*)wsb;
        emd_greedy_full_kernel<<<BATCH, 64, 0, stream>>>(pred, target, emd);
        emd_mean_kernel<<<1, 1, 0, stream>>>(emd, out);
    }
}

// Round 5
// 883.727 us; speedup vs baseline: 2.5718x; 1.3611x over previous
//
#include <hip/hip_runtime.h>
#include <stdint.h>

#define N 2048
#define BATCH 8
#define NROWS (BATCH * N)   // 16384
#define CAPN 256            // shortlist capacity per row
#define DEPTH 16            // phase-2 pipeline depth (rows in flight)

typedef unsigned long long u64;
typedef unsigned u32;

#define DEADK 0xFFFFFFFFFFFFFFFFull

// ---------------- DPP wave64 reductions -----------------------------------
__device__ __forceinline__ unsigned wave_umin_bcast(unsigned x) {
#define DPP_MIN(ctrl)                                                          \
  {                                                                            \
    unsigned t = (unsigned)__builtin_amdgcn_update_dpp((int)x, (int)x, ctrl,   \
                                                       0xf, 0xf, false);       \
    x = t < x ? t : x;                                                         \
  }
  DPP_MIN(0x111) DPP_MIN(0x112) DPP_MIN(0x114) DPP_MIN(0x118)
  DPP_MIN(0x142) DPP_MIN(0x143)
#undef DPP_MIN
  return (unsigned)__builtin_amdgcn_readlane((int)x, 63);
}

__device__ __forceinline__ unsigned wave_umax_bcast(unsigned x) {
#define DPP_MAX(ctrl)                                                          \
  {                                                                            \
    unsigned t = (unsigned)__builtin_amdgcn_update_dpp((int)x, (int)x, ctrl,   \
                                                       0xf, 0xf, false);       \
    x = t > x ? t : x;                                                         \
  }
  DPP_MAX(0x111) DPP_MAX(0x112) DPP_MAX(0x114) DPP_MAX(0x118)
  DPP_MAX(0x142) DPP_MAX(0x143)
#undef DPP_MAX
  return (unsigned)__builtin_amdgcn_readlane((int)x, 63);
}

#define DPP64_MIN(x, ctrl)                                                     \
  {                                                                            \
    u32 lo_ = (u32)(x), hi_ = (u32)((x) >> 32);                                \
    u32 tlo_ = (u32)__builtin_amdgcn_update_dpp((int)lo_, (int)lo_, (ctrl),    \
                                                0xf, 0xf, false);              \
    u32 thi_ = (u32)__builtin_amdgcn_update_dpp((int)hi_, (int)hi_, (ctrl),    \
                                                0xf, 0xf, false);              \
    u64 t_ = ((u64)thi_ << 32) | tlo_;                                         \
    x = t_ < x ? t_ : x;                                                       \
  }

__device__ __forceinline__ u64 wave_min64_l63(u64 x) {
  DPP64_MIN(x, 0x111) DPP64_MIN(x, 0x112) DPP64_MIN(x, 0x114)
  DPP64_MIN(x, 0x118) DPP64_MIN(x, 0x142) DPP64_MIN(x, 0x143)
  return x;
}

// Exact-order distance: ((dx*dx + dy*dy) + dz*dz), no FMA contraction, sqrtf.
#define DIST(qx, qy, qz, TX, TY, TZ, j, dout)                                  \
  do {                                                                         \
    _Pragma("clang fp contract(off)")                                          \
    float dx_ = (qx) - (TX)[j];                                                \
    float dy_ = (qy) - (TY)[j];                                                \
    float dz_ = (qz) - (TZ)[j];                                                \
    float s_ = dx_ * dx_ + dy_ * dy_ + dz_ * dz_;                              \
    dout = sqrtf(s_);                                                          \
  } while (0)

// ---------------- Phase 1a: tau-shortlist (proven R2-R4) -------------------
// Shortlist = COMPLETE set {key : d <= tau}, prefix-closed under (d,j) order.
__global__ __launch_bounds__(256, 1)
void emd_shortlist_kernel(const float* __restrict__ pred,
                          const float* __restrict__ target,
                          u64* __restrict__ keys,
                          u32* __restrict__ cnts) {
    __shared__ float tx[N], ty[N], tz[N];
    const int b  = blockIdx.x >> 9;
    const int r0 = (blockIdx.x & 511) << 2;
    const float* tb = target + (size_t)b * N * 3;

    for (int idx = threadIdx.x; idx < 3 * N; idx += 256) {
        float v = tb[idx];
        int n = idx / 3, c = idx - 3 * n;
        if (c == 0) tx[n] = v; else if (c == 1) ty[n] = v; else tz[n] = v;
    }
    __syncthreads();

    const int wid = threadIdx.x >> 6, lane = threadIdx.x & 63;
    const int i = r0 + wid;
    const size_t row = (size_t)b * N + i;
    const float* pb = pred + row * 3;
    const float qx = pb[0], qy = pb[1], qz = pb[2];

    float d[32];
    float m = 3.4e38f;
    #pragma unroll
    for (int c = 0; c < 32; ++c) {
        const int j = (c << 6) + lane;
        float dd;
        DIST(qx, qy, qz, tx, ty, tz, j, dd);
        d[c] = dd;
        m = fminf(m, dd);
    }

    unsigned mb = __float_as_uint(m);
    {   // pair-min (xor1 quad_perm): tau = max of 32 min-of-64 -> E[cnt]~130
        unsigned t = (unsigned)__builtin_amdgcn_update_dpp((int)mb, (int)mb,
                                                           0x0B1, 0xf, 0xf, false);
        mb = t < mb ? t : mb;
    }
    const unsigned tau = wave_umax_bcast(mb);
    const float tauf = __uint_as_float(tau);

    u64* krow = keys + row * (size_t)CAPN;
    unsigned base = 0;
    #pragma unroll
    for (int c = 0; c < 32; ++c) {
        const bool p = d[c] <= tauf;
        const u64 bm = __ballot(p);
        if (p) {
            unsigned off = base + (unsigned)__popcll(bm & ((1ull << lane) - 1ull));
            if (off < (unsigned)CAPN)
                krow[off] = ((u64)__float_as_uint(d[c]) << 32) |
                            (unsigned)((c << 6) + lane);
        }
        base += (unsigned)__popcll(bm);
    }
    if (lane == 0) cnts[row] = base;
}

// ---------------- Phase 1b: in-place sorted top-64 extraction --------------
#define CSWAP(a, b)                                                            \
  { u64 mn_ = (a) < (b) ? (a) : (b); u64 mx_ = (a) < (b) ? (b) : (a);          \
    (a) = mn_; (b) = mx_; }

__global__ __launch_bounds__(256, 1)
void emd_sort64_kernel(u64* __restrict__ keys, const u32* __restrict__ cnts) {
    const int wid = threadIdx.x >> 6, lane = threadIdx.x & 63;
    const size_t row = (size_t)blockIdx.x * 4 + wid;
    u64* krow = keys + row * (size_t)CAPN;

    const u32 cnt = cnts[row];
    const u32 lim = (cnt > (u32)CAPN) ? 0u : cnt;   // overflow -> no candidates

    u64 k0 = ((u32)lane       < lim) ? krow[lane      ] : DEADK;
    u64 k1 = ((u32)lane + 64  < lim) ? krow[lane + 64 ] : DEADK;
    u64 k2 = ((u32)lane + 128 < lim) ? krow[lane + 128] : DEADK;
    u64 k3 = ((u32)lane + 192 < lim) ? krow[lane + 192] : DEADK;

    CSWAP(k0, k1) CSWAP(k2, k3) CSWAP(k0, k2) CSWAP(k1, k3) CSWAP(k1, k2)

    u64 mykey = DEADK;
    for (int it = 0; it < 64; ++it) {
        u64 wm = wave_min64_l63(k0);
        u32 wlo = (u32)__builtin_amdgcn_readlane((int)(u32)wm, 63);
        u32 whi = (u32)__builtin_amdgcn_readlane((int)(u32)(wm >> 32), 63);
        if (whi == 0xFFFFFFFFu) break;            // all exhausted (cnt < 64)
        const u64 wkey = ((u64)whi << 32) | wlo;
        mykey = (lane == it) ? wkey : mykey;      // capture in lane `it`
        const bool eq = (k0 == wkey);             // unique (distinct j)
        k0 = eq ? k1 : k0; k1 = eq ? k2 : k1; k2 = eq ? k3 : k2;
        k3 = eq ? DEADK : k3;
    }
    krow[lane] = mykey;   // in-place: all reads consumed above
}

// ---------------- Phase 2: ballot-greedy, deep raw-key pipeline ------------
// Lane l holds the row's l-th smallest candidate (sorted by (d,j)), so the
// exact greedy winner = first alive lane (ballot+ffs). Keys stay RAW u64 in
// kk[] (2 VGPRs each) and are unpacked only at use, DEPTH rows after issue ->
// the compiler's vmcnt wait covers a 13-16-row-old load (latency hidden).
// Aliveness: consumed-bitmask word prefetched 3 rows early (+covers <= i) and
// ring {w0,w1} = last-2 winners (covers i+1, i+2). Exact; ballot==0 -> exact
// full-scan fallback against the complete bitmask.
__global__ __launch_bounds__(64, 1)
void emd_greedy_ballot_kernel(const float* __restrict__ pred,
                              const float* __restrict__ target,
                              const u64* __restrict__ keys,
                              float* __restrict__ batch_emd) {
    __shared__ float tx[N], ty[N], tz[N];
    __shared__ u32 maskLDS[64];                  // 2048-bit consumed bitmask

    const int lane = threadIdx.x;
    const int b = blockIdx.x;
    const float* pb = pred + (size_t)b * N * 3;
    const float* tb = target + (size_t)b * N * 3;

    for (int idx = lane; idx < 3 * N; idx += 64) {
        float vt = tb[idx];
        int n = idx / 3, c = idx - 3 * n;
        if (c == 0) tx[n] = vt; else if (c == 1) ty[n] = vt; else tz[n] = vt;
    }
    maskLDS[lane] = 0;
    u32 mw = 0;                                  // lane l mirrors word l
    // single wave: LDS is program-ordered; no barriers needed

    const u64* kb = keys + (size_t)b * N * (size_t)CAPN;

    u32 w0 = ~0u, w1 = ~0u;                      // last-2 winners (uniform)

    u64 kk[DEPTH];                               // RAW keys, unpack at use
    u32 wrd[DEPTH];                              // prefetched mask words
    #pragma unroll
    for (int s = 0; s < DEPTH; ++s) {
        kk[s] = kb[(size_t)s * CAPN + lane];
        wrd[s] = 0;                              // mask empty: rows 0..2 use it
    }

    double sum0 = 0.0, sum1 = 0.0;

    #pragma unroll 1
    for (int i0 = 0; i0 < N; i0 += DEPTH) {
        #pragma unroll
        for (int s = 0; s < DEPTH; ++s) {
            const int i = i0 + s;
            // ---- selection (branch-free hot path; first vmcnt use of kk[s])
            const u32 jv = (u32)kk[s];
            const u32 dv = (u32)(kk[s] >> 32);
            const bool alive = (((wrd[s] >> (jv & 31)) & 1u) == 0u) &
                               (dv != 0xFFFFFFFFu) &
                               (jv != w0) & (jv != w1);
            const u64 bal = __ballot(alive);
            u32 dw, jw;
            if (__builtin_expect(bal != 0ull, 1)) {
                const int L = __ffsll((long long)bal) - 1;
                dw = (u32)__builtin_amdgcn_readlane((int)dv, L);
                jw = (u32)__builtin_amdgcn_readlane((int)jv, L);
            } else {
                // exact full scan vs complete bitmask (rare: ~30/batch)
                const float qx = pb[3 * i], qy = pb[3 * i + 1], qz = pb[3 * i + 2];
                u32 dl = 0xFFFFFFFFu, jl = 0;
                #pragma unroll 4
                for (int c = 0; c < 32; ++c) {
                    const int j = (c << 6) + lane;
                    const u32 w = maskLDS[j >> 5];
                    float dd;
                    DIST(qx, qy, qz, tx, ty, tz, j, dd);
                    const u32 db = __float_as_uint(dd);
                    if ((((w >> (j & 31)) & 1u) == 0u) && db < dl) {
                        dl = db; jl = (u32)j;
                    }
                }
                const u32 dmin = wave_umin_bcast(dl);
                const u32 jc = (dl == dmin) ? jl : 0xFFFFFFFFu;
                jw = wave_umin_bcast(jc);
                dw = dmin;
            }
            // ---- commit ----
            if (s & 1) sum1 += (double)__uint_as_float(dw);
            else       sum0 += (double)__uint_as_float(dw);
            w1 = w0; w0 = jw;
            if (lane == (int)(jw >> 5)) { mw |= 1u << (jw & 31); maskLDS[lane] = mw; }
            // ---- prefetch mask word for row i+3 (kk there landed 13 rows ago)
            {
                const u32 j3 = (u32)kk[(s + 3) & (DEPTH - 1)];
                wrd[(s + 3) & (DEPTH - 1)] = maskLDS[(j3 >> 5) & 63];
            }
            // ---- insert row i+DEPTH into slot s (RAW; no unpack here!) ----
            {
                int r2 = i + DEPTH; if (r2 > N - 1) r2 = N - 1;  // tail clamp
                kk[s] = kb[(size_t)r2 * CAPN + lane];
            }
        }
    }

    if (lane == 0) batch_emd[b] = (float)((sum0 + sum1) / N);
}

// ---------------- exact full-scan helper (tiny-ws fallback kernel) --------
__device__ __forceinline__ u64 full_scan_row(
    int lane, float qx, float qy, float qz,
    const float* tx, const float* ty, const float* tz,
    const unsigned char* used) {
  u32 dl = 0xFFFFFFFFu, jl = 0u;
  #pragma unroll 8
  for (int c = 0; c < 32; ++c) {
    const int j = (c << 6) + lane;
    if (!used[j]) {
      float dd;
      DIST(qx, qy, qz, tx, ty, tz, j, dd);
      const u32 db = __float_as_uint(dd);
      if (db < dl) { dl = db; jl = (u32)j; }
    }
  }
  const u32 dmin = wave_umin_bcast(dl);
  const u32 jc = (dl == dmin) ? jl : 0xFFFFFFFFu;
  const u32 jmin = wave_umin_bcast(jc);
  return ((u64)dmin << 32) | jmin;
}

__global__ __launch_bounds__(64, 1)
void emd_greedy_full_kernel(const float* __restrict__ pred,
                            const float* __restrict__ target,
                            float* __restrict__ batch_emd) {
    __shared__ float tx[N], ty[N], tz[N];
    __shared__ float qxs[N], qys[N], qzs[N];
    __shared__ unsigned char used[N];

    const int lane = threadIdx.x;
    const int b = blockIdx.x;
    const float* pb = pred + (size_t)b * N * 3;
    const float* tb = target + (size_t)b * N * 3;

    for (int idx = lane; idx < 3 * N; idx += 64) {
        float vp = pb[idx], vt = tb[idx];
        int n = idx / 3, c = idx - 3 * n;
        if (c == 0)      { qxs[n] = vp; tx[n] = vt; }
        else if (c == 1) { qys[n] = vp; ty[n] = vt; }
        else             { qzs[n] = vp; tz[n] = vt; }
    }
    for (int j = lane; j < N; j += 64) used[j] = 0;

    double sum = 0.0;
    for (int i = 0; i < N; ++i) {
        u64 fs = full_scan_row(lane, qxs[i], qys[i], qzs[i], tx, ty, tz, used);
        sum += (double)__uint_as_float((u32)(fs >> 32));
        if (lane == 0) used[(u32)fs] = 1;
    }
    if (lane == 0) batch_emd[b] = (float)(sum / N);
}

__global__ void emd_mean_kernel(const float* __restrict__ batch_emd,
                                float* __restrict__ out) {
    double s = 0.0;
    for (int b = 0; b < BATCH; ++b) s += (double)batch_emd[b];
    out[0] = (float)(s / BATCH);
}

extern "C" void kernel_launch(void* const* d_in, const int* in_sizes, int n_in,
                              void* d_out, int out_size, void* d_ws, size_t ws_size,
                              hipStream_t stream) {
    const float* pred   = (const float*)d_in[0];
    const float* target = (const float*)d_in[1];
    float* out = (float*)d_out;
    char* wsb = (char*)d_ws;

    const size_t keysz = (size_t)NROWS * CAPN * 8;   // 33.6 MB
    const size_t cntsz = (size_t)NROWS * 4;

    if (ws_size >= keysz + cntsz + 32) {
        u64* keys = (u64*)wsb;
        u32* cnts = (u32*)(wsb + keysz);
        float* emd = (float*)(wsb + keysz + cntsz);
        emd_shortlist_kernel<<<NROWS / 4, 256, 0, stream>>>(pred, target, keys, cnts);
        emd_sort64_kernel<<<NROWS / 4, 256, 0, stream>>>(keys, cnts);
        emd_greedy_ballot_kernel<<<BATCH, 64, 0, stream>>>(pred, target, keys, emd);
        emd_mean_kernel<<<1, 1, 0, stream>>>(emd, out);
    } else {
        float* emd = (float*)wsb;
        emd_greedy_full_kernel<<<BATCH, 64, 0, stream>>>(pred, target, emd);
        emd_mean_kernel<<<1, 1, 0, stream>>>(emd, out);
    }
}